// Round 7
// baseline (302.501 us; speedup 1.0000x reference)
//
#include <hip/hip_runtime.h>
#include <math.h>

#define N_TOKENS 32768
#define DIM      4096
#define NE       64
#define TM       64              // tokens per block
#define BK       64              // K-chunk (floats); row = 256B = 16 slots of 16B
#define CHUNKS   (DIM / BK)      // 64
#define NBLK     (N_TOKENS / TM) // 512
#define EPS_GAP  2e-3f
#define REFINE_BLOCKS 1024

// d_out layout (float32 elements):
//   [0, 65536)        weights  [N_TOKENS][2]
//   [65536, 131072)   indices  [N_TOKENS][2]  stored as float
//   [131072, 131136)  new_bias [64]
//
// d_ws layout (4-byte units):
//   [0, 64)              ews_refine[64]  (float, zeroed per call)
//   [64]                 worklist count  (uint, zeroed per call)
//   [128, 32896)         per-block expert partials [512][64] (float)
//   [32896, 65664)       worklist token ids (int)
//   [65664, 327808)      W fragments: whi then wlo (bf16, 512KB each)
#define WOFF     65664
#define WL_OFF   32896
#define PART_OFF 128
#define WFRAG_ELEMS (512 * 512)   // 262144 bf16 per plane

typedef __bf16 bf16x8 __attribute__((ext_vector_type(8)));
typedef float  f32x16 __attribute__((ext_vector_type(16)));

#define SCHED0() __builtin_amdgcn_sched_barrier(0)
#define BAR()    __builtin_amdgcn_s_barrier()

// Convert W [64][4096] f32 -> fragment-ordered bf16 hi/lo.
// Fragment f = K16*2 + nt:  element (f, lane, b) =
//   W[nt*32 + (lane&31)][K16*16 + (lane>>5)*8 + b]
__global__ __launch_bounds__(256) void prep_w(
    const float* __restrict__ w, float* __restrict__ ws)
{
    __bf16* whi = (__bf16*)(ws + WOFF);
    __bf16* wlo = whi + WFRAG_ELEMS;
    const int tid  = blockIdx.x * 256 + threadIdx.x;  // 0..32767
    const int f    = tid >> 6, lane = tid & 63;
    const int nt   = f & 1,    K16  = f >> 1;
    const int e    = nt * 32 + (lane & 31);
    const int k    = K16 * 16 + (lane >> 5) * 8;
    const float4 a = *(const float4*)(w + (size_t)e * DIM + k);
    const float4 b = *(const float4*)(w + (size_t)e * DIM + k + 4);
    const float v[8] = {a.x, a.y, a.z, a.w, b.x, b.y, b.z, b.w};
    __bf16 h[8], l[8];
    #pragma unroll
    for (int i = 0; i < 8; ++i) {
        h[i] = (__bf16)v[i];
        l[i] = (__bf16)(v[i] - (float)h[i]);
    }
    *(bf16x8*)(whi + (size_t)tid * 8) = *(bf16x8*)h;
    *(bf16x8*)(wlo + (size_t)tid * 8) = *(bf16x8*)l;
}

// ---- f32 -> bf16 hi/lo via truncation bit-ops (residual ~2^-16 rel) ----
__device__ __forceinline__ unsigned pack_pair(float f0, float f1, float& r0, float& r1) {
    const unsigned u0 = __float_as_uint(f0), u1 = __float_as_uint(f1);
    const unsigned h0 = u0 & 0xFFFF0000u,   h1 = u1 & 0xFFFF0000u;
    r0 = f0 - __uint_as_float(h0);
    r1 = f1 - __uint_as_float(h1);
    return (u0 >> 16) | h1;
}
__device__ __forceinline__ void cvt8(const float4 a, const float4 b, uint4& h, uint4& l) {
    float r0, r1, r2, r3, r4, r5, r6, r7;
    h.x = pack_pair(a.x, a.y, r0, r1);
    h.y = pack_pair(a.z, a.w, r2, r3);
    h.z = pack_pair(b.x, b.y, r4, r5);
    h.w = pack_pair(b.z, b.w, r6, r7);
    l.x = (__float_as_uint(r0) >> 16) | (__float_as_uint(r1) & 0xFFFF0000u);
    l.y = (__float_as_uint(r2) >> 16) | (__float_as_uint(r3) & 0xFFFF0000u);
    l.z = (__float_as_uint(r4) >> 16) | (__float_as_uint(r5) & 0xFFFF0000u);
    l.w = (__float_as_uint(r6) >> 16) | (__float_as_uint(r7) & 0xFFFF0000u);
}

__device__ __forceinline__ void gload_lds16(const float* g, float* lds) {
    __builtin_amdgcn_global_load_lds(
        (const __attribute__((address_space(1))) unsigned*)g,
        (__attribute__((address_space(3))) unsigned*)lds, 16, 0, 0);
}

// One heavy kernel: 512 blocks x 64 tokens, full K, double-buffered LDS with
// counted vmcnt (never drains in loop) + raw barriers. In-block epilogue.
__global__ __launch_bounds__(256) void gate_main(
    const float* __restrict__ x, const float* __restrict__ bias,
    float* __restrict__ out, float* __restrict__ ws)
{
    __shared__ __align__(16) float xs[2][TM * BK];   // 2 x 16KB
    __shared__ float sc[TM][68];
    __shared__ float part[NE];
    __shared__ float sbias[NE];

    const __bf16* whi  = (const __bf16*)(ws + WOFF);
    const __bf16* wlo  = whi + WFRAG_ELEMS;
    unsigned* wl_count = (unsigned*)(ws + 64);
    float*    partials = ws + PART_OFF;
    int*      wl       = (int*)(ws + WL_OFF);

    const int t    = threadIdx.x;
    const int lane = t & 63;
    const int wave = t >> 6;
    const int mt   = wave >> 1;          // token half (0/1)
    const int nt   = wave & 1;           // expert half (0/1)
    const int tb   = blockIdx.x * TM;
    const int l31  = lane & 31, lhi = lane >> 5;

    if (t < NE) { sbias[t] = bias[t]; part[t] = 0.f; }

    // Staging: wave stages rows [wave*16, wave*16+16) of each chunk via 4
    // gload_lds (1KB each = 4 rows). lane l -> row R0+(l>>4), stored 16B-slot
    // (l&15); LDS dest linear, source column pre-swizzled: logical slot =
    // (l&15) ^ (row&15).
    size_t sofs[4];
    int    dofs[4];
    #pragma unroll
    for (int gl = 0; gl < 4; ++gl) {
        const int row  = wave * 16 + gl * 4 + (lane >> 4);
        const int slot = (lane & 15) ^ (row & 15);
        sofs[gl] = (size_t)(tb + row) * DIM + slot * 4;
        dofs[gl] = (wave * 16 + gl * 4) * BK;
    }

    const int a_row = mt * 32 + l31;     // token row this lane reads for MFMA A
    const int abase = a_row * BK;
    const int aswz  = a_row & 15;

    f32x16 acc0, acc12;
    #pragma unroll
    for (int i = 0; i < 16; ++i) { acc0[i] = 0.f; acc12[i] = 0.f; }

    // prologue: stage chunk 0 -> buf0, chunk 1 -> buf1
    #pragma unroll
    for (int gl = 0; gl < 4; ++gl) gload_lds16(x + sofs[gl],      &xs[0][dofs[gl]]);
    #pragma unroll
    for (int gl = 0; gl < 4; ++gl) gload_lds16(x + sofs[gl] + BK, &xs[1][dofs[gl]]);

    for (int c = 0; c < CHUNKS; ++c) {
        // invariant: outstanding = stage_c (4) [+ stage_{c+1} (4) if issued]
        if (c < CHUNKS - 1) { asm volatile("s_waitcnt vmcnt(4)" ::: "memory"); }
        else                { asm volatile("s_waitcnt vmcnt(0)" ::: "memory"); }
        SCHED0(); BAR(); SCHED0();       // all waves' stage_c complete

        const int K16c = c * 4;
        #pragma unroll
        for (int ks = 0; ks < 4; ++ks) {
            const int s0 = ks * 4 + lhi * 2;   // logical 16B slot pair
            const float4 fa = *(const float4*)&xs[c & 1][abase + ((s0 ^ aswz) << 2)];
            const float4 fb = *(const float4*)&xs[c & 1][abase + (((s0 + 1) ^ aswz) << 2)];
            uint4 h, l;
            cvt8(fa, fb, h, l);
            const size_t bidx = ((size_t)((K16c + ks) * 2 + nt) * 64 + lane) * 8;
            const bf16x8 bh = *(const bf16x8*)(whi + bidx);
            const bf16x8 bl = *(const bf16x8*)(wlo + bidx);
            const bf16x8 ah = __builtin_bit_cast(bf16x8, h);
            const bf16x8 al = __builtin_bit_cast(bf16x8, l);
            acc0  = __builtin_amdgcn_mfma_f32_32x32x16_bf16(ah, bh, acc0,  0, 0, 0);
            acc12 = __builtin_amdgcn_mfma_f32_32x32x16_bf16(al, bh, acc12, 0, 0, 0);
            acc12 = __builtin_amdgcn_mfma_f32_32x32x16_bf16(ah, bl, acc12, 0, 0, 0);
        }

        SCHED0(); BAR(); SCHED0();       // all waves done reading buf (c&1)
        if (c < CHUNKS - 2) {
            const size_t cofs = (size_t)(c + 2) * BK;
            #pragma unroll
            for (int gl = 0; gl < 4; ++gl)
                gload_lds16(x + sofs[gl] + cofs, &xs[c & 1][dofs[gl]]);
        }
    }

    // ---- epilogue: scores -> LDS, then top-3 per token ----
    // C/D layout: col = lane&31 (expert), row = (r&3)+8*(r>>2)+4*lhi (token)
    const int e = nt * 32 + l31;
    #pragma unroll
    for (int r = 0; r < 16; ++r) {
        const int tok = mt * 32 + (r & 3) + 8 * (r >> 2) + 4 * lhi;
        sc[tok][e] = acc0[r] + acc12[r];
    }
    __syncthreads();

    if (t < TM) {
        const int tok = t;
        float v1 = -3e38f, v2 = -3e38f, v3 = -3e38f;
        int   i1 = 0,      i2 = 0;
        #pragma unroll 8
        for (int ei = 0; ei < NE; ++ei) {
            const float s = sc[tok][ei] + sbias[ei];
            if (s > v1)      { v3 = v2; v2 = v1; i2 = i1; v1 = s; i1 = ei; }
            else if (s > v2) { v3 = v2; v2 = s;  i2 = ei; }
            else if (s > v3) { v3 = s; }
        }
        const bool risky = (v1 - v2 < EPS_GAP) || (v2 - v3 < EPS_GAP);
        if (risky) {
            const int pos = (int)atomicAdd(wl_count, 1u);
            wl[pos] = tb + tok;                  // refined later in fp64
        } else {
            const float ex = expf(v2 - v1);      // <= 1
            const float w1 = 1.f / (1.f + ex);
            const float w2 = ex * w1;
            const size_t g = (size_t)(tb + tok) * 2;
            *(float2*)(out + g)                        = make_float2(w1, w2);
            *(float2*)(out + (size_t)N_TOKENS * 2 + g) = make_float2((float)i1, (float)i2);
            atomicAdd(&part[i1], w1);
            atomicAdd(&part[i2], w2);
        }
    }
    __syncthreads();
    if (t < NE) partials[(size_t)blockIdx.x * NE + t] = part[t];
}

// fp64 re-score of near-tie tokens: exact ordering vs the true scores.
__global__ __launch_bounds__(256) void gate_refine(
    const float* __restrict__ x,
    const float* __restrict__ w,
    const float* __restrict__ bias,
    float* __restrict__ out,
    float* __restrict__ ws)
{
    float*          ews_ref  = ws;
    const unsigned* wl_count = (const unsigned*)(ws + 64);
    const int*      wl       = (const int*)(ws + WL_OFF);

    const int t = threadIdx.x;
    const int e = t >> 2;        // expert 0..63
    const int q = t & 3;         // quarter of K
    __shared__ double sc[NE];

    const unsigned count = *wl_count;
    for (unsigned it = blockIdx.x; it < count; it += gridDim.x) {
        const int tok = wl[it];
        const float* xr = x + (size_t)tok * DIM;
        const float* wr = w + (size_t)e * DIM;
        double s = 0.0;
        const int k0 = q * (DIM / 4), k1 = k0 + DIM / 4;
        for (int k = k0; k < k1; k += 4) {
            const float4 a = *(const float4*)(xr + k);
            const float4 b = *(const float4*)(wr + k);
            s += (double)a.x * (double)b.x;
            s += (double)a.y * (double)b.y;
            s += (double)a.z * (double)b.z;
            s += (double)a.w * (double)b.w;
        }
        s += __shfl_xor(s, 1);
        s += __shfl_xor(s, 2);
        if (q == 0) sc[e] = s + (double)bias[e];
        __syncthreads();

        if (t == 0) {
            double v1 = -1e300, v2 = -1e300;
            int i1 = 0, i2 = 0;
            for (int j = 0; j < NE; ++j) {
                const double sv = sc[j];
                if (sv > v1)      { v2 = v1; i2 = i1; v1 = sv; i1 = j; }
                else if (sv > v2) { v2 = sv; i2 = j; }
            }
            const double ex = exp(v2 - v1);
            const double w1 = 1.0 / (1.0 + ex);
            const double w2 = ex * w1;
            const size_t g = (size_t)tok * 2;
            *(float2*)(out + g)                        = make_float2((float)w1, (float)w2);
            *(float2*)(out + (size_t)N_TOKENS * 2 + g) = make_float2((float)i1, (float)i2);
            atomicAdd(&ews_ref[i1], (float)w1);
            atomicAdd(&ews_ref[i2], (float)w2);
        }
        __syncthreads();
    }
}

__global__ void gate_bias(
    const float* __restrict__ bias,
    const float* __restrict__ target,
    const float* __restrict__ ws,
    float* __restrict__ out)
{
    const int e = threadIdx.x;   // 64 threads, one wave
    const float* partials = ws + PART_OFF;
    float v = ws[e];             // refined-token contribution
    for (int b = 0; b < NBLK; ++b) v += partials[(size_t)b * NE + e];
    float total = v;
    #pragma unroll
    for (int off = 32; off > 0; off >>= 1)
        total += __shfl_xor(total, off);
    const float nb = bias[e] + 0.001f * ((target[e] * total - v) / total);
    out[(size_t)N_TOKENS * 4 + e] = nb;
}

extern "C" void kernel_launch(void* const* d_in, const int* in_sizes, int n_in,
                              void* d_out, int out_size, void* d_ws, size_t ws_size,
                              hipStream_t stream) {
    const float* x      = (const float*)d_in[0];
    const float* w      = (const float*)d_in[1];
    const float* bias   = (const float*)d_in[2];
    const float* target = (const float*)d_in[3];
    float* out = (float*)d_out;
    float* ws  = (float*)d_ws;

    hipMemsetAsync(ws, 0, 128 * sizeof(float), stream);   // ews_ref + wl_count
    prep_w     <<<128, 256, 0, stream>>>(w, ws);
    gate_main  <<<NBLK, 256, 0, stream>>>(x, bias, out, ws);
    gate_refine<<<REFINE_BLOCKS, 256, 0, stream>>>(x, w, bias, out, ws);
    gate_bias  <<<1, 64, 0, stream>>>(bias, target, ws, out);
}

// Round 8
// 295.988 us; speedup vs baseline: 1.0220x; 1.0220x over previous
//
#include <hip/hip_runtime.h>
#include <math.h>

#define N_TOKENS 32768
#define DIM      4096
#define NE       64
#define KS       4                      // K-split
#define KSPAN    (DIM / KS)             // 1024
#define BKF      32                     // floats per chunk (per row)
#define NCH      (KSPAN / BKF)          // 32 chunks
#define NBLK_MAIN (N_TOKENS / 64 * KS)  // 2048 blocks (2 waves x 32 tokens)
#define NBLK_POST (N_TOKENS / 256)      // 128
#define EPS_GAP  2e-3f
#define REFINE_BLOCKS 1024

// d_out layout (float32 elements):
//   [0, 65536)        weights  [N_TOKENS][2]
//   [65536, 131072)   indices  [N_TOKENS][2]  stored as float
//   [131072, 131136)  new_bias [64]
//
// d_ws layout (4-byte units):
//   [0, 64)              ews_refine[64]  (float, zeroed per call)
//   [64]                 worklist count  (uint, zeroed per call)
//   [128, 8320)          per-post-block expert partials [128][64] (float)
//   [16384, 49152)       worklist token ids (int)
//   [65664, 327808)      W fragments: whi then wlo (bf16, 512KB each)
//   [524288, 8912896)    partial scores psc[4][N_TOKENS][64] (f32, 33.5MB)
#define WOFF     65664
#define WL_OFF   16384
#define PART_OFF 128
#define PSC_OFF  524288
#define WFRAG_ELEMS (512 * 512)

typedef __bf16 bf16x8 __attribute__((ext_vector_type(8)));
typedef float  f32x16 __attribute__((ext_vector_type(16)));

#define SB0() __builtin_amdgcn_sched_barrier(0)

// Convert W [64][4096] f32 -> fragment-ordered bf16 hi/lo.
// Fragment f = K16*2 + nt:  element (f, lane, b) =
//   W[nt*32 + (lane&31)][K16*16 + (lane>>5)*8 + b]
__global__ __launch_bounds__(256) void prep_w(
    const float* __restrict__ w, float* __restrict__ ws)
{
    __bf16* whi = (__bf16*)(ws + WOFF);
    __bf16* wlo = whi + WFRAG_ELEMS;
    const int tid  = blockIdx.x * 256 + threadIdx.x;  // 0..32767
    const int f    = tid >> 6, lane = tid & 63;
    const int nt   = f & 1,    K16  = f >> 1;
    const int e    = nt * 32 + (lane & 31);
    const int k    = K16 * 16 + (lane >> 5) * 8;
    const float4 a = *(const float4*)(w + (size_t)e * DIM + k);
    const float4 b = *(const float4*)(w + (size_t)e * DIM + k + 4);
    const float v[8] = {a.x, a.y, a.z, a.w, b.x, b.y, b.z, b.w};
    __bf16 h[8], l[8];
    #pragma unroll
    for (int i = 0; i < 8; ++i) {
        h[i] = (__bf16)v[i];
        l[i] = (__bf16)(v[i] - (float)h[i]);
    }
    *(bf16x8*)(whi + (size_t)tid * 8) = *(bf16x8*)h;
    *(bf16x8*)(wlo + (size_t)tid * 8) = *(bf16x8*)l;
}

// ---- f32 -> bf16 hi/lo via truncation bit-ops ----
__device__ __forceinline__ unsigned pack_pair(float f0, float f1, float& r0, float& r1) {
    const unsigned u0 = __float_as_uint(f0), u1 = __float_as_uint(f1);
    const unsigned h0 = u0 & 0xFFFF0000u,   h1 = u1 & 0xFFFF0000u;
    r0 = f0 - __uint_as_float(h0);
    r1 = f1 - __uint_as_float(h1);
    return (u0 >> 16) | h1;
}
__device__ __forceinline__ void cvt8(const float4 a, const float4 b, uint4& h, uint4& l) {
    float r0, r1, r2, r3, r4, r5, r6, r7;
    h.x = pack_pair(a.x, a.y, r0, r1);
    h.y = pack_pair(a.z, a.w, r2, r3);
    h.z = pack_pair(b.x, b.y, r4, r5);
    h.w = pack_pair(b.z, b.w, r6, r7);
    l.x = (__float_as_uint(r0) >> 16) | (__float_as_uint(r1) & 0xFFFF0000u);
    l.y = (__float_as_uint(r2) >> 16) | (__float_as_uint(r3) & 0xFFFF0000u);
    l.z = (__float_as_uint(r4) >> 16) | (__float_as_uint(r5) & 0xFFFF0000u);
    l.w = (__float_as_uint(r6) >> 16) | (__float_as_uint(r7) & 0xFFFF0000u);
}

__device__ __forceinline__ void gload_lds16(const float* g, float* lds) {
    __builtin_amdgcn_global_load_lds(
        (const __attribute__((address_space(1))) unsigned*)g,
        (__attribute__((address_space(3))) unsigned*)lds, 16, 0, 0);
}

struct BS { bf16x8 h[2][2]; bf16x8 l[2][2]; };   // [k16-in-chunk][nt]

// Barrier-free, wave-independent streaming GEMM.
// Block b: token tile (b>>2)*64, K-quarter b&3. Wave w: tokens +w*32.
// LDS per wave: 2 x 4KB chunk buffers (32 rows x 128B), 8-slot XOR swizzle.
__global__ __launch_bounds__(128) void gate_main(
    const float* __restrict__ x, float* __restrict__ ws)
{
    __shared__ __align__(16) float xsf[4096];    // 16KB: wave w owns [w*2048, +2048)

    const __bf16* whi = (const __bf16*)(ws + WOFF);
    const __bf16* wlo = whi + WFRAG_ELEMS;
    float*        psc = ws + PSC_OFF;

    const int t    = threadIdx.x;
    const int lane = t & 63;
    const int w    = t >> 6;
    const int tile = blockIdx.x >> 2;
    const int kq   = blockIdx.x & 3;
    const int tb   = tile * 64 + w * 32;
    const int kbeg = kq * KSPAN;
    const int l31  = lane & 31, lhi = lane >> 5;
    const int dbase = w * 2048;                  // floats

    // staging source offsets: g covers rows g*8..+8; lane -> row g*8+(l>>3),
    // stored slot l&7, logical slot (l&7)^(l>>3)  (row&7 == l>>3)
    size_t sofs[4];
    #pragma unroll
    for (int g = 0; g < 4; ++g) {
        const int row = g * 8 + (lane >> 3);
        const int col = ((lane & 7) ^ (lane >> 3)) * 4;   // floats
        sofs[g] = (size_t)(tb + row) * DIM + kbeg + col;
    }

    const int arow  = l31;
    const int aswz  = arow & 7;

    f32x16 acc0, acc1;
    #pragma unroll
    for (int i = 0; i < 16; ++i) { acc0[i] = 0.f; acc1[i] = 0.f; }

    BS BA, BB;

    #define LOADB(B, c) {                                                     \
        _Pragma("unroll")                                                     \
        for (int ks = 0; ks < 2; ++ks) {                                      \
            _Pragma("unroll")                                                 \
            for (int nt = 0; nt < 2; ++nt) {                                  \
                const size_t f = (size_t)((kq * 64 + (c) * 2 + ks) * 2 + nt); \
                (B).h[ks][nt] = *(const bf16x8*)(whi + (f * 64 + lane) * 8);  \
                (B).l[ks][nt] = *(const bf16x8*)(wlo + (f * 64 + lane) * 8);  \
            }                                                                 \
        } }

    #define STAGE(c, p) {                                                     \
        _Pragma("unroll")                                                     \
        for (int g = 0; g < 4; ++g)                                           \
            gload_lds16(x + sofs[g] + (size_t)(c) * BKF,                      \
                        &xsf[dbase + (p) * 1024 + g * 256]); }

    #define COMPUTE(p, B) {                                                   \
        const int ab = dbase + (p) * 1024 + arow * 32;                        \
        _Pragma("unroll")                                                     \
        for (int ks = 0; ks < 2; ++ks) {                                      \
            const int s0 = ks * 4 + lhi * 2;                                  \
            const float4 fa = *(const float4*)&xsf[ab + ((s0 ^ aswz) << 2)];  \
            const float4 fb = *(const float4*)&xsf[ab + (((s0+1) ^ aswz) << 2)]; \
            uint4 hh, ll;                                                     \
            cvt8(fa, fb, hh, ll);                                             \
            const bf16x8 ah = __builtin_bit_cast(bf16x8, hh);                 \
            const bf16x8 al = __builtin_bit_cast(bf16x8, ll);                 \
            acc0 = __builtin_amdgcn_mfma_f32_32x32x16_bf16(ah, (B).h[ks][0], acc0, 0,0,0); \
            acc1 = __builtin_amdgcn_mfma_f32_32x32x16_bf16(ah, (B).h[ks][1], acc1, 0,0,0); \
            acc0 = __builtin_amdgcn_mfma_f32_32x32x16_bf16(al, (B).h[ks][0], acc0, 0,0,0); \
            acc1 = __builtin_amdgcn_mfma_f32_32x32x16_bf16(al, (B).h[ks][1], acc1, 0,0,0); \
            acc0 = __builtin_amdgcn_mfma_f32_32x32x16_bf16(ah, (B).l[ks][0], acc0, 0,0,0); \
            acc1 = __builtin_amdgcn_mfma_f32_32x32x16_bf16(ah, (B).l[ks][1], acc1, 0,0,0); \
        } }

    // prologue — FIFO: [bA0(8), s0(4), bB1(8), s1(4)] = 16 + 8 = 24 ops
    LOADB(BA, 0); STAGE(0, 0); LOADB(BB, 1); STAGE(1, 1);

    for (int cc = 0; cc < NCH / 2; ++cc) {
        const int c0 = 2 * cc;
        // chunk c0 (buf0, BA): drain through s_{c0} -> 12 remain
        asm volatile("s_waitcnt vmcnt(12)" ::: "memory");
        SB0();
        COMPUTE(0, BA);
        SB0();
        { const int cn = (c0 + 2 < NCH) ? c0 + 2 : NCH - 1;
          LOADB(BA, cn); STAGE(cn, 0); }
        SB0();
        // chunk c0+1 (buf1, BB)
        asm volatile("s_waitcnt vmcnt(12)" ::: "memory");
        SB0();
        COMPUTE(1, BB);
        SB0();
        { const int cn = (c0 + 3 < NCH) ? c0 + 3 : NCH - 1;
          LOADB(BB, cn); STAGE(cn, 1); }
        SB0();
    }
    #undef LOADB
    #undef STAGE
    #undef COMPUTE

    // C/D layout: col = lane&31 (expert), row = (r&3)+8*(r>>2)+4*lhi (token)
    float* p = psc + ((size_t)kq * N_TOKENS + tb) * NE;
    #pragma unroll
    for (int r = 0; r < 16; ++r) {
        const int tok = (r & 3) + 8 * (r >> 2) + 4 * lhi;
        p[(size_t)tok * NE + l31]      = acc0[r];
        p[(size_t)tok * NE + l31 + 32] = acc1[r];
    }
}

// Sum 4 K-quarters + bias, top-3 scan, risky-flag or write outputs.
__global__ __launch_bounds__(256) void gate_post(
    const float* __restrict__ bias,
    float* __restrict__ out,
    float* __restrict__ ws)
{
    __shared__ float sbias[NE];
    __shared__ float part[NE];
    unsigned* wl_count = (unsigned*)(ws + 64);
    float*    partials = ws + PART_OFF;
    int*      wl       = (int*)(ws + WL_OFF);
    const float* psc   = ws + PSC_OFF;
    const size_t PL    = (size_t)N_TOKENS * NE;

    const int t = threadIdx.x;
    if (t < NE) { sbias[t] = bias[t]; part[t] = 0.f; }
    __syncthreads();

    const int tok = blockIdx.x * 256 + t;
    const float* p = psc + (size_t)tok * NE;

    float v1 = -3e38f, v2 = -3e38f, v3 = -3e38f;
    int   i1 = 0,      i2 = 0;
    #pragma unroll
    for (int g = 0; g < 16; ++g) {
        const float4 a = *(const float4*)(p + g * 4);
        const float4 b = *(const float4*)(p + PL + g * 4);
        const float4 c = *(const float4*)(p + 2 * PL + g * 4);
        const float4 d = *(const float4*)(p + 3 * PL + g * 4);
        float sv4[4] = {(a.x + b.x) + (c.x + d.x), (a.y + b.y) + (c.y + d.y),
                        (a.z + b.z) + (c.z + d.z), (a.w + b.w) + (c.w + d.w)};
        #pragma unroll
        for (int j = 0; j < 4; ++j) {
            const float sv = sv4[j] + sbias[g * 4 + j];
            const int   e  = g * 4 + j;
            if (sv > v1)      { v3 = v2; v2 = v1; i2 = i1; v1 = sv; i1 = e; }
            else if (sv > v2) { v3 = v2; v2 = sv; i2 = e; }
            else if (sv > v3) { v3 = sv; }
        }
    }
    const bool risky = (v1 - v2 < EPS_GAP) || (v2 - v3 < EPS_GAP);
    if (risky) {
        const int pos = (int)atomicAdd(wl_count, 1u);
        wl[pos] = tok;                       // refined later in fp64
    } else {
        const float ex = expf(v2 - v1);      // <= 1
        const float w1 = 1.f / (1.f + ex);
        const float w2 = ex * w1;
        const size_t g = (size_t)tok * 2;
        *(float2*)(out + g)                        = make_float2(w1, w2);
        *(float2*)(out + (size_t)N_TOKENS * 2 + g) = make_float2((float)i1, (float)i2);
        atomicAdd(&part[i1], w1);
        atomicAdd(&part[i2], w2);
    }
    __syncthreads();
    if (t < NE) partials[(size_t)blockIdx.x * NE + t] = part[t];
}

// fp64 re-score of near-tie tokens: exact ordering vs the true scores.
__global__ __launch_bounds__(256) void gate_refine(
    const float* __restrict__ x,
    const float* __restrict__ w,
    const float* __restrict__ bias,
    float* __restrict__ out,
    float* __restrict__ ws)
{
    float*          ews_ref  = ws;
    const unsigned* wl_count = (const unsigned*)(ws + 64);
    const int*      wl       = (const int*)(ws + WL_OFF);

    const int t = threadIdx.x;
    const int e = t >> 2;        // expert 0..63
    const int q = t & 3;         // quarter of K
    __shared__ double sc[NE];

    const unsigned count = *wl_count;
    for (unsigned it = blockIdx.x; it < count; it += gridDim.x) {
        const int tok = wl[it];
        const float* xr = x + (size_t)tok * DIM;
        const float* wr = w + (size_t)e * DIM;
        double s = 0.0;
        const int k0 = q * (DIM / 4), k1 = k0 + DIM / 4;
        for (int k = k0; k < k1; k += 4) {
            const float4 a = *(const float4*)(xr + k);
            const float4 b = *(const float4*)(wr + k);
            s += (double)a.x * (double)b.x;
            s += (double)a.y * (double)b.y;
            s += (double)a.z * (double)b.z;
            s += (double)a.w * (double)b.w;
        }
        s += __shfl_xor(s, 1);
        s += __shfl_xor(s, 2);
        if (q == 0) sc[e] = s + (double)bias[e];
        __syncthreads();

        if (t == 0) {
            double v1 = -1e300, v2 = -1e300;
            int i1 = 0, i2 = 0;
            for (int j = 0; j < NE; ++j) {
                const double sv = sc[j];
                if (sv > v1)      { v2 = v1; i2 = i1; v1 = sv; i1 = j; }
                else if (sv > v2) { v2 = sv; i2 = j; }
            }
            const double ex = exp(v2 - v1);
            const double w1 = 1.0 / (1.0 + ex);
            const double w2 = ex * w1;
            const size_t g = (size_t)tok * 2;
            *(float2*)(out + g)                        = make_float2((float)w1, (float)w2);
            *(float2*)(out + (size_t)N_TOKENS * 2 + g) = make_float2((float)i1, (float)i2);
            atomicAdd(&ews_ref[i1], (float)w1);
            atomicAdd(&ews_ref[i2], (float)w2);
        }
        __syncthreads();
    }
}

__global__ void gate_bias(
    const float* __restrict__ bias,
    const float* __restrict__ target,
    const float* __restrict__ ws,
    float* __restrict__ out)
{
    const int e = threadIdx.x;   // 64 threads, one wave
    const float* partials = ws + PART_OFF;
    float v = ws[e];             // refined-token contribution
    for (int b = 0; b < NBLK_POST; ++b) v += partials[(size_t)b * NE + e];
    float total = v;
    #pragma unroll
    for (int off = 32; off > 0; off >>= 1)
        total += __shfl_xor(total, off);
    const float nb = bias[e] + 0.001f * ((target[e] * total - v) / total);
    out[(size_t)N_TOKENS * 4 + e] = nb;
}

extern "C" void kernel_launch(void* const* d_in, const int* in_sizes, int n_in,
                              void* d_out, int out_size, void* d_ws, size_t ws_size,
                              hipStream_t stream) {
    const float* x      = (const float*)d_in[0];
    const float* w      = (const float*)d_in[1];
    const float* bias   = (const float*)d_in[2];
    const float* target = (const float*)d_in[3];
    float* out = (float*)d_out;
    float* ws  = (float*)d_ws;

    hipMemsetAsync(ws, 0, 128 * sizeof(float), stream);   // ews_ref + wl_count
    prep_w     <<<128, 256, 0, stream>>>(w, ws);
    gate_main  <<<NBLK_MAIN, 128, 0, stream>>>(x, ws);
    gate_post  <<<NBLK_POST, 256, 0, stream>>>(bias, out, ws);
    gate_refine<<<REFINE_BLOCKS, 256, 0, stream>>>(x, w, bias, out, ws);
    gate_bias  <<<1, 64, 0, stream>>>(bias, target, ws, out);
}